// Round 2
// baseline (1601.993 us; speedup 1.0000x reference)
//
#include <hip/hip_runtime.h>

// ---------------------------------------------------------------------------
// StoryMemoryBlock  (B=4, T=4096, D=1024, DF=4096, K=15, S=8, SD=32)
// bf16 MFMA for all matmuls (m97-structure 128x128 tile GEMM), fp32 for
// norms/sigmoid/softmax/scan. Fused epilogues. Workspace kept to ~216 MiB
// via time-phased aliasing + row-chunked FFN intermediate.
// ---------------------------------------------------------------------------

#define BN_T 4096
#define DIM 1024
#define BT_TOT (4 * 4096)          // 16384 rows
#define NKER 15

typedef __bf16 bf16x8 __attribute__((ext_vector_type(8)));
typedef float  f32x4  __attribute__((ext_vector_type(4)));

__device__ __forceinline__ unsigned short f2bf(float f) {
    unsigned int u = __float_as_uint(f);
    u = u + 0x7FFFu + ((u >> 16) & 1u);           // RNE
    return (unsigned short)(u >> 16);
}
__device__ __forceinline__ float bf2f(unsigned short s) {
    return __uint_as_float(((unsigned int)s) << 16);
}

__device__ __forceinline__ void gload_lds16(const unsigned short* g, unsigned short* l) {
    __builtin_amdgcn_global_load_lds((const __attribute__((address_space(1))) void*)g,
                                     (__attribute__((address_space(3))) void*)l, 16, 0, 0);
}

// ---------------- weight conversion helpers --------------------------------
__global__ void k_cvt(const float* __restrict__ in, unsigned short* __restrict__ out, int n4) {
    int i = blockIdx.x * 256 + threadIdx.x;
    if (i < n4) {
        float4 v = ((const float4*)in)[i];
        ushort4 o;
        o.x = f2bf(v.x); o.y = f2bf(v.y); o.z = f2bf(v.z); o.w = f2bf(v.w);
        ((ushort4*)out)[i] = o;
    }
}

// pad write_gate(8)/write_val(32)/read_query(8) into one 128x1024 bf16 matrix
__global__ void k_build_small(const float* __restrict__ wg, const float* __restrict__ wv,
                              const float* __restrict__ rq, unsigned short* __restrict__ out) {
    int i = blockIdx.x * 256 + threadIdx.x;      // 128*1024
    if (i >= 128 * 1024) return;
    int r = i >> 10, k = i & 1023;
    float v = 0.f;
    if (r < 8)       v = wg[r * 1024 + k];
    else if (r < 40) v = wv[(r - 8) * 1024 + k];
    else if (r < 48) v = rq[(r - 40) * 1024 + k];
    out[i] = f2bf(v);
}

// interleave Wg/Wu rows at 16-row granularity: row j -> blk=j>>5, r=j&31;
// r<16 : Wg[blk*16+r], else Wu[blk*16+r-16].  (8192 x 1024)
__global__ void k_build_wcat(const float* __restrict__ wgw, const float* __restrict__ wuw,
                             unsigned short* __restrict__ out) {
    int i = blockIdx.x * 256 + threadIdx.x;      // 8192*1024
    if (i >= 8192 * 1024) return;
    int j = i >> 10, k = i & 1023;
    int blk = j >> 5, r = j & 31;
    float v = (r < 16) ? wgw[(blk * 16 + r) * 1024 + k]
                       : wuw[(blk * 16 + (r - 16)) * 1024 + k];
    out[i] = f2bf(v);
}

// ---------------- rmsnorm (fp32 in -> bf16 out) ----------------------------
__global__ __launch_bounds__(256) void k_rmsnorm(const float* __restrict__ x,
                                                 const float* __restrict__ w,
                                                 unsigned short* __restrict__ out) {
    int row = blockIdx.x;
    const float4* xr = (const float4*)(x + (size_t)row * DIM);
    float4 v = xr[threadIdx.x];
    float ss = v.x * v.x + v.y * v.y + v.z * v.z + v.w * v.w;
    #pragma unroll
    for (int off = 32; off > 0; off >>= 1) ss += __shfl_down(ss, off, 64);
    __shared__ float p[4];
    if ((threadIdx.x & 63) == 0) p[threadIdx.x >> 6] = ss;
    __syncthreads();
    float tot = p[0] + p[1] + p[2] + p[3];
    float rms = rsqrtf(tot * (1.0f / DIM) + 1e-6f);
    float4 wv = ((const float4*)w)[threadIdx.x];
    ushort4 o;
    o.x = f2bf(v.x * rms * wv.x);
    o.y = f2bf(v.y * rms * wv.y);
    o.z = f2bf(v.z * rms * wv.z);
    o.w = f2bf(v.w * rms * wv.w);
    ((ushort4*)(out + (size_t)row * DIM))[threadIdx.x] = o;
}

// ---------------- GEMM: C = A(MxK) * Bw(NxK)^T, bf16 in, f32 acc -----------
// MODE 0: outF = C              (f32)
// MODE 1: outF = resid + C      (f32)   (resid may alias outF element-wise)
// MODE 2: outB = C              (bf16)
// MODE 3: SwiGLU pairs: nf even = g, nf odd = u -> outB = silu(g)*u, width N/2
template <int MODE>
__global__ __launch_bounds__(256) void k_gemm(const unsigned short* __restrict__ A,
                                              const unsigned short* __restrict__ Bw,
                                              int M, int N, int K,
                                              const float* resid,
                                              float* outF,
                                              unsigned short* outB) {
    __shared__ unsigned short As[128 * 32];
    __shared__ unsigned short Bs[128 * 32];
    const int tid = threadIdx.x;
    const int l   = tid & 63;
    const int wid = tid >> 6;
    const int wr  = wid >> 1, wc = wid & 1;
    const int m0  = blockIdx.x * 128, n0 = blockIdx.y * 128;

    f32x4 acc[4][4];
    #pragma unroll
    for (int i = 0; i < 4; ++i)
        #pragma unroll
        for (int j = 0; j < 4; ++j) acc[i][j] = f32x4{0.f, 0.f, 0.f, 0.f};

    const int c0 = tid, c1 = tid + 256;
    const unsigned short* a0 = A + (size_t)(m0 + (c0 >> 2)) * K + (c0 & 3) * 8;
    const unsigned short* a1 = A + (size_t)(m0 + (c1 >> 2)) * K + (c1 & 3) * 8;
    const unsigned short* b0 = Bw + (size_t)(n0 + (c0 >> 2)) * K + (c0 & 3) * 8;
    const unsigned short* b1 = Bw + (size_t)(n0 + (c1 >> 2)) * K + (c1 & 3) * 8;
    unsigned short* lA0 = &As[c0 * 8];
    unsigned short* lA1 = &As[c1 * 8];
    unsigned short* lB0 = &Bs[c0 * 8];
    unsigned short* lB1 = &Bs[c1 * 8];

    for (int kt = 0; kt < K; kt += 32) {
        gload_lds16(a0 + kt, lA0);
        gload_lds16(a1 + kt, lA1);
        gload_lds16(b0 + kt, lB0);
        gload_lds16(b1 + kt, lB1);
        __syncthreads();   // compiler drains vmcnt before barrier

        bf16x8 af[4], bfr[4];
        #pragma unroll
        for (int mf = 0; mf < 4; ++mf)
            af[mf] = *(const bf16x8*)&As[(wr * 64 + mf * 16 + (l & 15)) * 32 + (l >> 4) * 8];
        #pragma unroll
        for (int nf = 0; nf < 4; ++nf)
            bfr[nf] = *(const bf16x8*)&Bs[(wc * 64 + nf * 16 + (l & 15)) * 32 + (l >> 4) * 8];
        #pragma unroll
        for (int mf = 0; mf < 4; ++mf)
            #pragma unroll
            for (int nf = 0; nf < 4; ++nf)
                acc[mf][nf] = __builtin_amdgcn_mfma_f32_16x16x32_bf16(af[mf], bfr[nf], acc[mf][nf], 0, 0, 0);
        __syncthreads();
    }

    const int rbase = m0 + wr * 64 + (l >> 4) * 4;
    const int cbase = n0 + wc * 64 + (l & 15);
    if constexpr (MODE == 3) {
        const int halfN = N >> 1;
        const int cb = (n0 >> 1) + wc * 32 + (l & 15);
        #pragma unroll
        for (int mf = 0; mf < 4; ++mf)
            #pragma unroll
            for (int p = 0; p < 2; ++p)
                #pragma unroll
                for (int r = 0; r < 4; ++r) {
                    float g = acc[mf][2 * p][r];
                    float u = acc[mf][2 * p + 1][r];
                    float s = g / (1.f + expf(-g));
                    int row = rbase + mf * 16 + r;
                    outB[(size_t)row * halfN + cb + p * 16] = f2bf(s * u);
                }
    } else {
        #pragma unroll
        for (int mf = 0; mf < 4; ++mf)
            #pragma unroll
            for (int nf = 0; nf < 4; ++nf)
                #pragma unroll
                for (int r = 0; r < 4; ++r) {
                    int row = rbase + mf * 16 + r;
                    int col = cbase + nf * 16;
                    size_t idx = (size_t)row * N + col;
                    float v = acc[mf][nf][r];
                    if constexpr (MODE == 0) outF[idx] = v;
                    if constexpr (MODE == 1) outF[idx] = resid[idx] + v;
                    if constexpr (MODE == 2) outB[idx] = f2bf(v);
                }
    }
}

// ---------------- gated causal depthwise conv ------------------------------
// gv: (BT, 2048) bf16, cols 0..1023 gate logits, 1024..2047 val
// cg[bt,d] = sigmoid(gate) * sum_k cw[d,k] * val[bt-14+k, d]
__global__ __launch_bounds__(256) void k_conv(const unsigned short* __restrict__ gv,
                                              const float* __restrict__ cw,
                                              unsigned short* __restrict__ cg) {
    __shared__ unsigned short vs[78 * 256];
    const int d  = blockIdx.x * 256 + threadIdx.x;
    const int t0 = blockIdx.y * 64;
    const int b  = blockIdx.z;
    const size_t base = (size_t)b * BN_T * 2048;
    for (int r = 0; r < 78; ++r) {
        int t = t0 - 14 + r;
        vs[r * 256 + threadIdx.x] = (t >= 0) ? gv[base + (size_t)t * 2048 + 1024 + d]
                                             : (unsigned short)0;
    }
    float wreg[NKER];
    #pragma unroll
    for (int k = 0; k < NKER; ++k) wreg[k] = cw[d * NKER + k];
    __syncthreads();
    for (int tl = 0; tl < 64; ++tl) {
        float acc = 0.f;
        #pragma unroll
        for (int k = 0; k < NKER; ++k)
            acc += wreg[k] * bf2f(vs[(tl + k) * 256 + threadIdx.x]);
        int t = t0 + tl;
        float gl = bf2f(gv[base + (size_t)t * 2048 + d]);
        float g  = 1.f / (1.f + expf(-gl));
        cg[((size_t)b * BN_T + t) * DIM + d] = f2bf(acc * g);
    }
}

// ---------------- small projections postprocess ----------------------------
// logits: (BT,128) f32 -> wg=sigmoid(l[0:8]), wv=l[8:40], rw=softmax(l[40:48])
__global__ void k_small(const float* __restrict__ logits, float* __restrict__ wg,
                        float* __restrict__ wv, float* __restrict__ rw) {
    int row = blockIdx.x * 256 + threadIdx.x;
    if (row >= BT_TOT) return;
    const float* lp = logits + (size_t)row * 128;
    #pragma unroll
    for (int s = 0; s < 8; ++s) wg[row * 8 + s] = 1.f / (1.f + expf(-lp[s]));
    #pragma unroll
    for (int e = 0; e < 32; ++e) wv[row * 32 + e] = lp[8 + e];
    float m = -1e30f;
    #pragma unroll
    for (int s = 0; s < 8; ++s) m = fmaxf(m, lp[40 + s]);
    float ex[8], sum = 0.f;
    #pragma unroll
    for (int s = 0; s < 8; ++s) { ex[s] = expf(lp[40 + s] - m); sum += ex[s]; }
    float inv = 1.f / sum;
    #pragma unroll
    for (int s = 0; s < 8; ++s) rw[row * 8 + s] = ex[s] * inv;
}

// ---------------- gated slot recurrence (serial over T) --------------------
// cur = w*v + (1-w)*cur ;  stackw[bt, s*32+sd] = bf16(read_w * cur)
__global__ __launch_bounds__(256) void k_scan(const float* __restrict__ wg,
                                              const float* __restrict__ wv,
                                              const float* __restrict__ rw,
                                              const float* __restrict__ mem0,
                                              unsigned short* __restrict__ stackw,
                                              float* __restrict__ curout) {
    const int b  = blockIdx.x;           // 4
    const int s  = threadIdx.x >> 5;     // 0..7
    const int sd = threadIdx.x & 31;     // 0..31
    float cur = mem0[(b * 8 + s) * 32 + sd];
    const size_t rbase = (size_t)b * BN_T;
    float w0 = wg[rbase * 8 + s];
    float v0 = wv[rbase * 32 + sd];
    float r0 = rw[rbase * 8 + s];
    for (int t = 0; t < BN_T; ++t) {
        float w1 = 0.f, v1 = 0.f, r1 = 0.f;
        if (t + 1 < BN_T) {
            size_t nbt = rbase + t + 1;
            w1 = wg[nbt * 8 + s];
            v1 = wv[nbt * 32 + sd];
            r1 = rw[nbt * 8 + s];
        }
        cur = w0 * v0 + (1.f - w0) * cur;
        stackw[(rbase + t) * 256 + threadIdx.x] = f2bf(r0 * cur);
        w0 = w1; v0 = v1; r0 = r1;
    }
    curout[(b * 8 + s) * 32 + sd] = cur;
}

// ---------------------------------------------------------------------------
extern "C" void kernel_launch(void* const* d_in, const int* in_sizes, int n_in,
                              void* d_out, int out_size, void* d_ws, size_t ws_size,
                              hipStream_t stream) {
    const float* x      = (const float*)d_in[0];
    const float* mem0   = (const float*)d_in[1];
    const float* ln1    = (const float*)d_in[2];
    const float* muw    = (const float*)d_in[3];
    const float* cw     = (const float*)d_in[4];
    const float* mdw    = (const float*)d_in[5];
    const float* lnm    = (const float*)d_in[6];
    const float* wgate  = (const float*)d_in[7];
    const float* wval   = (const float*)d_in[8];
    const float* rquery = (const float*)d_in[9];
    const float* rout   = (const float*)d_in[10];
    const float* ln2    = (const float*)d_in[11];
    const float* wgw    = (const float*)d_in[12];
    const float* wuw    = (const float*)d_in[13];
    const float* wow    = (const float*)d_in[14];
    float* out = (float*)d_out;
    char* ws = (char*)d_ws;

    // ---- workspace layout: 216 MiB total via time-phased aliasing ----
    // R region (96 MiB): phase A {gv 64MB | cg 32MB}; phase B {logits 8MB,
    // stackw 8MB, wgf/wvf/rwf ~3MB}; phase C {ff chunk 64MB}.
    char* R = ws;
    unsigned short* gv     = (unsigned short*)(R + 0);
    unsigned short* cg     = (unsigned short*)(R + 67108864);
    float*          logits = (float*)(R + 0);
    unsigned short* stackw = (unsigned short*)(R + 8388608);
    float*          wgf    = (float*)(R + 16777216);
    float*          wvf    = (float*)(R + 17301504);
    float*          rwf    = (float*)(R + 19398656);
    unsigned short* ff     = (unsigned short*)(R + 0);          // 8192x4096 bf16 chunk
    unsigned short* h_buf  = (unsigned short*)(ws + 100663296); // 32 MiB
    float*          x2     = (float*)(ws + 134217728);          // 64 MiB
    // W region (24 MiB): JIT weight staging
    unsigned short* w_any  = (unsigned short*)(ws + 201326592); // reused slot
    unsigned short* w_cat  = (unsigned short*)(ws + 201326592); // 16 MiB
    unsigned short* w_wo   = (unsigned short*)(ws + 218103808); // 8 MiB
    // total = 226,492,416 bytes (~216 MiB)

    // ---- mixer ----
    k_cvt<<<dim3(2048), 256, 0, stream>>>(muw, w_any, 524288);            // 2048x1024
    k_rmsnorm<<<dim3(BT_TOT), 256, 0, stream>>>(x, ln1, h_buf);
    k_gemm<2><<<dim3(128, 16), 256, 0, stream>>>(h_buf, w_any, BT_TOT, 2048, 1024,
                                                 nullptr, nullptr, gv);
    k_conv<<<dim3(4, 64, 4), 256, 0, stream>>>(gv, cw, cg);
    k_cvt<<<dim3(1024), 256, 0, stream>>>(mdw, w_any, 262144);            // 1024x1024
    k_gemm<1><<<dim3(128, 8), 256, 0, stream>>>(cg, w_any, BT_TOT, 1024, 1024,
                                                x, x2, nullptr);

    // ---- story memory ----
    k_rmsnorm<<<dim3(BT_TOT), 256, 0, stream>>>(x2, lnm, h_buf);
    k_build_small<<<dim3(512), 256, 0, stream>>>(wgate, wval, rquery, w_any);
    k_gemm<0><<<dim3(128, 1), 256, 0, stream>>>(h_buf, w_any, BT_TOT, 128, 1024,
                                                nullptr, logits, nullptr);
    k_small<<<dim3(64), 256, 0, stream>>>(logits, wgf, wvf, rwf);
    k_scan<<<dim3(4), 256, 0, stream>>>(wgf, wvf, rwf, mem0, stackw, out + 16777216);
    k_cvt<<<dim3(256), 256, 0, stream>>>(rout, w_any, 65536);             // 1024x256
    k_gemm<1><<<dim3(128, 8), 256, 0, stream>>>(stackw, w_any, BT_TOT, 1024, 256,
                                                x2, x2, nullptr);          // in-place resid add

    // ---- SwiGLU FFN (row-chunked x2 so ff fits in R) ----
    k_rmsnorm<<<dim3(BT_TOT), 256, 0, stream>>>(x2, ln2, h_buf);
    k_build_wcat<<<dim3(32768), 256, 0, stream>>>(wgw, wuw, w_cat);
    k_cvt<<<dim3(4096), 256, 0, stream>>>(wow, w_wo, 1048576);            // 1024x4096
    for (int c = 0; c < 2; ++c) {
        const size_t ro = (size_t)c * 8192;
        k_gemm<3><<<dim3(64, 64), 256, 0, stream>>>(h_buf + ro * 1024, w_cat,
                                                    8192, 8192, 1024,
                                                    nullptr, nullptr, ff);
        k_gemm<1><<<dim3(64, 8), 256, 0, stream>>>(ff, w_wo, 8192, 1024, 4096,
                                                   x2 + ro * 1024, out + ro * 1024, nullptr);
    }
}

// Round 4
// 1174.169 us; speedup vs baseline: 1.3644x; 1.3644x over previous
//
#include <hip/hip_runtime.h>

// ---------------------------------------------------------------------------
// StoryMemoryBlock  (B=4, T=4096, D=1024, DF=4096, K=15, S=8, SD=32)
// bf16 MFMA for all matmuls (m97-structure 128x128 tile GEMM), fp32 for
// norms/sigmoid/softmax/scan. Fused epilogues. Workspace ~216 MiB.
// R2 change: serial k_scan (444us, 0.18% occupancy) -> 3-phase chunked
// affine scan (parallel over 256 chunks of 16 steps).
// R3: resubmit (broker timeout, no signal).
// ---------------------------------------------------------------------------

#define BN_T 4096
#define DIM 1024
#define BT_TOT (4 * 4096)          // 16384 rows
#define NKER 15
#define CHUNK 16
#define NCHUNK 256                 // 4096 / 16

typedef __bf16 bf16x8 __attribute__((ext_vector_type(8)));
typedef float  f32x4  __attribute__((ext_vector_type(4)));

__device__ __forceinline__ unsigned short f2bf(float f) {
    unsigned int u = __float_as_uint(f);
    u = u + 0x7FFFu + ((u >> 16) & 1u);           // RNE
    return (unsigned short)(u >> 16);
}
__device__ __forceinline__ float bf2f(unsigned short s) {
    return __uint_as_float(((unsigned int)s) << 16);
}

__device__ __forceinline__ void gload_lds16(const unsigned short* g, unsigned short* l) {
    __builtin_amdgcn_global_load_lds((const __attribute__((address_space(1))) void*)g,
                                     (__attribute__((address_space(3))) void*)l, 16, 0, 0);
}

// ---------------- weight conversion helpers --------------------------------
__global__ void k_cvt(const float* __restrict__ in, unsigned short* __restrict__ out, int n4) {
    int i = blockIdx.x * 256 + threadIdx.x;
    if (i < n4) {
        float4 v = ((const float4*)in)[i];
        ushort4 o;
        o.x = f2bf(v.x); o.y = f2bf(v.y); o.z = f2bf(v.z); o.w = f2bf(v.w);
        ((ushort4*)out)[i] = o;
    }
}

// pad write_gate(8)/write_val(32)/read_query(8) into one 128x1024 bf16 matrix
__global__ void k_build_small(const float* __restrict__ wg, const float* __restrict__ wv,
                              const float* __restrict__ rq, unsigned short* __restrict__ out) {
    int i = blockIdx.x * 256 + threadIdx.x;      // 128*1024
    if (i >= 128 * 1024) return;
    int r = i >> 10, k = i & 1023;
    float v = 0.f;
    if (r < 8)       v = wg[r * 1024 + k];
    else if (r < 40) v = wv[(r - 8) * 1024 + k];
    else if (r < 48) v = rq[(r - 40) * 1024 + k];
    out[i] = f2bf(v);
}

// interleave Wg/Wu rows at 16-row granularity: row j -> blk=j>>5, r=j&31;
// r<16 : Wg[blk*16+r], else Wu[blk*16+r-16].  (8192 x 1024)
__global__ void k_build_wcat(const float* __restrict__ wgw, const float* __restrict__ wuw,
                             unsigned short* __restrict__ out) {
    int i = blockIdx.x * 256 + threadIdx.x;      // 8192*1024
    if (i >= 8192 * 1024) return;
    int j = i >> 10, k = i & 1023;
    int blk = j >> 5, r = j & 31;
    float v = (r < 16) ? wgw[(blk * 16 + r) * 1024 + k]
                       : wuw[(blk * 16 + (r - 16)) * 1024 + k];
    out[i] = f2bf(v);
}

// ---------------- rmsnorm (fp32 in -> bf16 out) ----------------------------
__global__ __launch_bounds__(256) void k_rmsnorm(const float* __restrict__ x,
                                                 const float* __restrict__ w,
                                                 unsigned short* __restrict__ out) {
    int row = blockIdx.x;
    const float4* xr = (const float4*)(x + (size_t)row * DIM);
    float4 v = xr[threadIdx.x];
    float ss = v.x * v.x + v.y * v.y + v.z * v.z + v.w * v.w;
    #pragma unroll
    for (int off = 32; off > 0; off >>= 1) ss += __shfl_down(ss, off, 64);
    __shared__ float p[4];
    if ((threadIdx.x & 63) == 0) p[threadIdx.x >> 6] = ss;
    __syncthreads();
    float tot = p[0] + p[1] + p[2] + p[3];
    float rms = rsqrtf(tot * (1.0f / DIM) + 1e-6f);
    float4 wv = ((const float4*)w)[threadIdx.x];
    ushort4 o;
    o.x = f2bf(v.x * rms * wv.x);
    o.y = f2bf(v.y * rms * wv.y);
    o.z = f2bf(v.z * rms * wv.z);
    o.w = f2bf(v.w * rms * wv.w);
    ((ushort4*)(out + (size_t)row * DIM))[threadIdx.x] = o;
}

// ---------------- GEMM: C = A(MxK) * Bw(NxK)^T, bf16 in, f32 acc -----------
// MODE 0: outF = C              (f32)
// MODE 1: outF = resid + C      (f32)   (resid may alias outF element-wise)
// MODE 2: outB = C              (bf16)
// MODE 3: SwiGLU pairs: nf even = g, nf odd = u -> outB = silu(g)*u, width N/2
template <int MODE>
__global__ __launch_bounds__(256) void k_gemm(const unsigned short* __restrict__ A,
                                              const unsigned short* __restrict__ Bw,
                                              int M, int N, int K,
                                              const float* resid,
                                              float* outF,
                                              unsigned short* outB) {
    __shared__ unsigned short As[128 * 32];
    __shared__ unsigned short Bs[128 * 32];
    const int tid = threadIdx.x;
    const int l   = tid & 63;
    const int wid = tid >> 6;
    const int wr  = wid >> 1, wc = wid & 1;
    const int m0  = blockIdx.x * 128, n0 = blockIdx.y * 128;

    f32x4 acc[4][4];
    #pragma unroll
    for (int i = 0; i < 4; ++i)
        #pragma unroll
        for (int j = 0; j < 4; ++j) acc[i][j] = f32x4{0.f, 0.f, 0.f, 0.f};

    const int c0 = tid, c1 = tid + 256;
    const unsigned short* a0 = A + (size_t)(m0 + (c0 >> 2)) * K + (c0 & 3) * 8;
    const unsigned short* a1 = A + (size_t)(m0 + (c1 >> 2)) * K + (c1 & 3) * 8;
    const unsigned short* b0 = Bw + (size_t)(n0 + (c0 >> 2)) * K + (c0 & 3) * 8;
    const unsigned short* b1 = Bw + (size_t)(n0 + (c1 >> 2)) * K + (c1 & 3) * 8;
    unsigned short* lA0 = &As[c0 * 8];
    unsigned short* lA1 = &As[c1 * 8];
    unsigned short* lB0 = &Bs[c0 * 8];
    unsigned short* lB1 = &Bs[c1 * 8];

    for (int kt = 0; kt < K; kt += 32) {
        gload_lds16(a0 + kt, lA0);
        gload_lds16(a1 + kt, lA1);
        gload_lds16(b0 + kt, lB0);
        gload_lds16(b1 + kt, lB1);
        __syncthreads();   // compiler drains vmcnt before barrier

        bf16x8 af[4], bfr[4];
        #pragma unroll
        for (int mf = 0; mf < 4; ++mf)
            af[mf] = *(const bf16x8*)&As[(wr * 64 + mf * 16 + (l & 15)) * 32 + (l >> 4) * 8];
        #pragma unroll
        for (int nf = 0; nf < 4; ++nf)
            bfr[nf] = *(const bf16x8*)&Bs[(wc * 64 + nf * 16 + (l & 15)) * 32 + (l >> 4) * 8];
        #pragma unroll
        for (int mf = 0; mf < 4; ++mf)
            #pragma unroll
            for (int nf = 0; nf < 4; ++nf)
                acc[mf][nf] = __builtin_amdgcn_mfma_f32_16x16x32_bf16(af[mf], bfr[nf], acc[mf][nf], 0, 0, 0);
        __syncthreads();
    }

    const int rbase = m0 + wr * 64 + (l >> 4) * 4;
    const int cbase = n0 + wc * 64 + (l & 15);
    if constexpr (MODE == 3) {
        const int halfN = N >> 1;
        const int cb = (n0 >> 1) + wc * 32 + (l & 15);
        #pragma unroll
        for (int mf = 0; mf < 4; ++mf)
            #pragma unroll
            for (int p = 0; p < 2; ++p)
                #pragma unroll
                for (int r = 0; r < 4; ++r) {
                    float g = acc[mf][2 * p][r];
                    float u = acc[mf][2 * p + 1][r];
                    float s = g / (1.f + expf(-g));
                    int row = rbase + mf * 16 + r;
                    outB[(size_t)row * halfN + cb + p * 16] = f2bf(s * u);
                }
    } else {
        #pragma unroll
        for (int mf = 0; mf < 4; ++mf)
            #pragma unroll
            for (int nf = 0; nf < 4; ++nf)
                #pragma unroll
                for (int r = 0; r < 4; ++r) {
                    int row = rbase + mf * 16 + r;
                    int col = cbase + nf * 16;
                    size_t idx = (size_t)row * N + col;
                    float v = acc[mf][nf][r];
                    if constexpr (MODE == 0) outF[idx] = v;
                    if constexpr (MODE == 1) outF[idx] = resid[idx] + v;
                    if constexpr (MODE == 2) outB[idx] = f2bf(v);
                }
    }
}

// ---------------- gated causal depthwise conv ------------------------------
// gv: (BT, 2048) bf16, cols 0..1023 gate logits, 1024..2047 val
// cg[bt,d] = sigmoid(gate) * sum_k cw[d,k] * val[bt-14+k, d]
__global__ __launch_bounds__(256) void k_conv(const unsigned short* __restrict__ gv,
                                              const float* __restrict__ cw,
                                              unsigned short* __restrict__ cg) {
    __shared__ unsigned short vs[78 * 256];
    const int d  = blockIdx.x * 256 + threadIdx.x;
    const int t0 = blockIdx.y * 64;
    const int b  = blockIdx.z;
    const size_t base = (size_t)b * BN_T * 2048;
    for (int r = 0; r < 78; ++r) {
        int t = t0 - 14 + r;
        vs[r * 256 + threadIdx.x] = (t >= 0) ? gv[base + (size_t)t * 2048 + 1024 + d]
                                             : (unsigned short)0;
    }
    float wreg[NKER];
    #pragma unroll
    for (int k = 0; k < NKER; ++k) wreg[k] = cw[d * NKER + k];
    __syncthreads();
    for (int tl = 0; tl < 64; ++tl) {
        float acc = 0.f;
        #pragma unroll
        for (int k = 0; k < NKER; ++k)
            acc += wreg[k] * bf2f(vs[(tl + k) * 256 + threadIdx.x]);
        int t = t0 + tl;
        float gl = bf2f(gv[base + (size_t)t * 2048 + d]);
        float g  = 1.f / (1.f + expf(-gl));
        cg[((size_t)b * BN_T + t) * DIM + d] = f2bf(acc * g);
    }
}

// ---------------- small projections postprocess ----------------------------
// logits: (BT,128) f32 -> wg=sigmoid(l[0:8]), wv=l[8:40], rw=softmax(l[40:48])
__global__ void k_small(const float* __restrict__ logits, float* __restrict__ wg,
                        float* __restrict__ wv, float* __restrict__ rw) {
    int row = blockIdx.x * 256 + threadIdx.x;
    if (row >= BT_TOT) return;
    const float* lp = logits + (size_t)row * 128;
    #pragma unroll
    for (int s = 0; s < 8; ++s) wg[row * 8 + s] = 1.f / (1.f + expf(-lp[s]));
    #pragma unroll
    for (int e = 0; e < 32; ++e) wv[row * 32 + e] = lp[8 + e];
    float m = -1e30f;
    #pragma unroll
    for (int s = 0; s < 8; ++s) m = fmaxf(m, lp[40 + s]);
    float ex[8], sum = 0.f;
    #pragma unroll
    for (int s = 0; s < 8; ++s) { ex[s] = expf(lp[40 + s] - m); sum += ex[s]; }
    float inv = 1.f / sum;
    #pragma unroll
    for (int s = 0; s < 8; ++s) rw[row * 8 + s] = ex[s] * inv;
}

// ---------------- chunked affine scan (3 phases) ---------------------------
// recurrence per (b,s,sd): cur = w*v + (1-w)*cur  ==  cur = A*cur + B affine.
// phase 1: per 16-step chunk compute A=prod(1-w), B=state-from-zero.
__global__ __launch_bounds__(256) void k_scan1(const float* __restrict__ wg,
                                               const float* __restrict__ wv,
                                               float* __restrict__ Ac,
                                               float* __restrict__ Bc) {
    const int c = blockIdx.x, b = blockIdx.y;
    const int s = threadIdx.x >> 5, sd = threadIdx.x & 31;
    const size_t tbase = (size_t)b * BN_T + (size_t)c * CHUNK;
    float A = 1.f, Bst = 0.f;
    #pragma unroll
    for (int i = 0; i < CHUNK; ++i) {
        float w = wg[(tbase + i) * 8 + s];
        float v = wv[(tbase + i) * 32 + sd];
        Bst = w * v + (1.f - w) * Bst;
        A *= (1.f - w);
    }
    const size_t idx = ((size_t)b * NCHUNK + c) * 256 + threadIdx.x;
    Ac[idx] = A;
    Bc[idx] = Bst;
}

// phase 2: serial combine over 256 chunks; store per-chunk initial state.
__global__ __launch_bounds__(256) void k_scan2(const float* __restrict__ Ac,
                                               const float* __restrict__ Bc,
                                               const float* __restrict__ mem0,
                                               float* __restrict__ S0,
                                               float* __restrict__ curout) {
    const int b = blockIdx.x;
    const int tid = threadIdx.x;
    float st = mem0[b * 256 + tid];
    size_t idx = (size_t)b * NCHUNK * 256 + tid;
    float a0 = Ac[idx], b0 = Bc[idx];
    for (int c = 0; c < NCHUNK; ++c) {
        float a1 = 0.f, b1 = 0.f;
        if (c + 1 < NCHUNK) {              // prefetch next chunk coeffs
            a1 = Ac[idx + 256];
            b1 = Bc[idx + 256];
        }
        S0[idx] = st;
        st = a0 * st + b0;
        a0 = a1; b0 = b1;
        idx += 256;
    }
    curout[b * 256 + tid] = st;
}

// phase 3: replay chunk from corrected initial state, write bf16(rw*cur).
__global__ __launch_bounds__(256) void k_scan3(const float* __restrict__ wg,
                                               const float* __restrict__ wv,
                                               const float* __restrict__ rw,
                                               const float* __restrict__ S0,
                                               unsigned short* __restrict__ stackw) {
    const int c = blockIdx.x, b = blockIdx.y;
    const int s = threadIdx.x >> 5, sd = threadIdx.x & 31;
    const size_t tbase = (size_t)b * BN_T + (size_t)c * CHUNK;
    float cur = S0[((size_t)b * NCHUNK + c) * 256 + threadIdx.x];
    #pragma unroll
    for (int i = 0; i < CHUNK; ++i) {
        float w = wg[(tbase + i) * 8 + s];
        float v = wv[(tbase + i) * 32 + sd];
        cur = w * v + (1.f - w) * cur;
        stackw[(tbase + i) * 256 + threadIdx.x] = f2bf(rw[(tbase + i) * 8 + s] * cur);
    }
}

// ---------------------------------------------------------------------------
extern "C" void kernel_launch(void* const* d_in, const int* in_sizes, int n_in,
                              void* d_out, int out_size, void* d_ws, size_t ws_size,
                              hipStream_t stream) {
    const float* x      = (const float*)d_in[0];
    const float* mem0   = (const float*)d_in[1];
    const float* ln1    = (const float*)d_in[2];
    const float* muw    = (const float*)d_in[3];
    const float* cw     = (const float*)d_in[4];
    const float* mdw    = (const float*)d_in[5];
    const float* lnm    = (const float*)d_in[6];
    const float* wgate  = (const float*)d_in[7];
    const float* wval   = (const float*)d_in[8];
    const float* rquery = (const float*)d_in[9];
    const float* rout   = (const float*)d_in[10];
    const float* ln2    = (const float*)d_in[11];
    const float* wgw    = (const float*)d_in[12];
    const float* wuw    = (const float*)d_in[13];
    const float* wow    = (const float*)d_in[14];
    float* out = (float*)d_out;
    char* ws = (char*)d_ws;

    // ---- workspace layout: ~216 MiB via time-phased aliasing ----
    // R region (96 MiB): phase A {gv 64MB | cg 32MB}; phase B {logits 8MB,
    // stackw 8MB, wgf/wvf/rwf, scan coeffs}; phase C {ff chunk 64MB}.
    char* R = ws;
    unsigned short* gv     = (unsigned short*)(R + 0);
    unsigned short* cg     = (unsigned short*)(R + 67108864);
    float*          logits = (float*)(R + 0);
    unsigned short* stackw = (unsigned short*)(R + 8388608);
    float*          wgf    = (float*)(R + 16777216);
    float*          wvf    = (float*)(R + 17301504);
    float*          rwf    = (float*)(R + 19398656);
    float*          scanA  = (float*)(R + 20971520);   // 1 MiB (4*256*256 f32)
    float*          scanB  = (float*)(R + 22020096);   // 1 MiB
    float*          scanS0 = (float*)(R + 23068672);   // 1 MiB
    unsigned short* ff     = (unsigned short*)(R + 0);          // 8192x4096 bf16 chunk
    unsigned short* h_buf  = (unsigned short*)(ws + 100663296); // 32 MiB
    float*          x2     = (float*)(ws + 134217728);          // 64 MiB
    unsigned short* w_any  = (unsigned short*)(ws + 201326592); // reused slot
    unsigned short* w_cat  = (unsigned short*)(ws + 201326592); // 16 MiB
    unsigned short* w_wo   = (unsigned short*)(ws + 218103808); // 8 MiB
    // total = 226,492,416 bytes (~216 MiB)

    // ---- mixer ----
    k_cvt<<<dim3(2048), 256, 0, stream>>>(muw, w_any, 524288);            // 2048x1024
    k_rmsnorm<<<dim3(BT_TOT), 256, 0, stream>>>(x, ln1, h_buf);
    k_gemm<2><<<dim3(128, 16), 256, 0, stream>>>(h_buf, w_any, BT_TOT, 2048, 1024,
                                                 nullptr, nullptr, gv);
    k_conv<<<dim3(4, 64, 4), 256, 0, stream>>>(gv, cw, cg);
    k_cvt<<<dim3(1024), 256, 0, stream>>>(mdw, w_any, 262144);            // 1024x1024
    k_gemm<1><<<dim3(128, 8), 256, 0, stream>>>(cg, w_any, BT_TOT, 1024, 1024,
                                                x, x2, nullptr);

    // ---- story memory ----
    k_rmsnorm<<<dim3(BT_TOT), 256, 0, stream>>>(x2, lnm, h_buf);
    k_build_small<<<dim3(512), 256, 0, stream>>>(wgate, wval, rquery, w_any);
    k_gemm<0><<<dim3(128, 1), 256, 0, stream>>>(h_buf, w_any, BT_TOT, 128, 1024,
                                                nullptr, logits, nullptr);
    k_small<<<dim3(64), 256, 0, stream>>>(logits, wgf, wvf, rwf);
    k_scan1<<<dim3(NCHUNK, 4), 256, 0, stream>>>(wgf, wvf, scanA, scanB);
    k_scan2<<<dim3(4), 256, 0, stream>>>(scanA, scanB, mem0, scanS0, out + 16777216);
    k_scan3<<<dim3(NCHUNK, 4), 256, 0, stream>>>(wgf, wvf, rwf, scanS0, stackw);
    k_cvt<<<dim3(256), 256, 0, stream>>>(rout, w_any, 65536);             // 1024x256
    k_gemm<1><<<dim3(128, 8), 256, 0, stream>>>(stackw, w_any, BT_TOT, 1024, 256,
                                                x2, x2, nullptr);          // in-place resid add

    // ---- SwiGLU FFN (row-chunked x2 so ff fits in R) ----
    k_rmsnorm<<<dim3(BT_TOT), 256, 0, stream>>>(x2, ln2, h_buf);
    k_build_wcat<<<dim3(32768), 256, 0, stream>>>(wgw, wuw, w_cat);
    k_cvt<<<dim3(4096), 256, 0, stream>>>(wow, w_wo, 1048576);            // 1024x4096
    for (int c = 0; c < 2; ++c) {
        const size_t ro = (size_t)c * 8192;
        k_gemm<3><<<dim3(64, 64), 256, 0, stream>>>(h_buf + ro * 1024, w_cat,
                                                    8192, 8192, 1024,
                                                    nullptr, nullptr, ff);
        k_gemm<1><<<dim3(64, 8), 256, 0, stream>>>(ff, w_wo, 8192, 1024, 4096,
                                                   x2 + ro * 1024, out + ro * 1024, nullptr);
    }
}

// Round 5
// 976.319 us; speedup vs baseline: 1.6408x; 1.2026x over previous
//
#include <hip/hip_runtime.h>

// ---------------------------------------------------------------------------
// StoryMemoryBlock  (B=4, T=4096, D=1024, DF=4096, K=15, S=8, SD=32)
// R5: big GEMMs moved to 256x256 / 8-wave / BK=64 kernel with T2 LDS swizzle
// (pre-swizzled global src + linear global_load_lds + swizzled ds_read),
// counted vmcnt(2) double-buffer (raw s_barrier, never __syncthreads),
// setprio around MFMA quadrants. FFN2 runs full-M (256 wgs) when ws_size
// allows the 248MiB layout; otherwise chunked fallback on the 128² kernel.
// ---------------------------------------------------------------------------

#define BN_T 4096
#define DIM 1024
#define BT_TOT (4 * 4096)          // 16384 rows
#define NKER 15
#define CHUNK 16
#define NCHUNK 256                 // 4096 / 16

typedef __bf16 bf16x8 __attribute__((ext_vector_type(8)));
typedef float  f32x4  __attribute__((ext_vector_type(4)));

__device__ __forceinline__ unsigned short f2bf(float f) {
    unsigned int u = __float_as_uint(f);
    u = u + 0x7FFFu + ((u >> 16) & 1u);           // RNE
    return (unsigned short)(u >> 16);
}
__device__ __forceinline__ float bf2f(unsigned short s) {
    return __uint_as_float(((unsigned int)s) << 16);
}

__device__ __forceinline__ void gload_lds16(const unsigned short* g, unsigned short* l) {
    __builtin_amdgcn_global_load_lds((const __attribute__((address_space(1))) void*)g,
                                     (__attribute__((address_space(3))) void*)l, 16, 0, 0);
}

#define SBAR() asm volatile("s_barrier" ::: "memory")

// ---------------- weight conversion helpers --------------------------------
__global__ void k_cvt(const float* __restrict__ in, unsigned short* __restrict__ out, int n4) {
    int i = blockIdx.x * 256 + threadIdx.x;
    if (i < n4) {
        float4 v = ((const float4*)in)[i];
        ushort4 o;
        o.x = f2bf(v.x); o.y = f2bf(v.y); o.z = f2bf(v.z); o.w = f2bf(v.w);
        ((ushort4*)out)[i] = o;
    }
}

__global__ void k_build_small(const float* __restrict__ wg, const float* __restrict__ wv,
                              const float* __restrict__ rq, unsigned short* __restrict__ out) {
    int i = blockIdx.x * 256 + threadIdx.x;      // 128*1024
    if (i >= 128 * 1024) return;
    int r = i >> 10, k = i & 1023;
    float v = 0.f;
    if (r < 8)       v = wg[r * 1024 + k];
    else if (r < 40) v = wv[(r - 8) * 1024 + k];
    else if (r < 48) v = rq[(r - 40) * 1024 + k];
    out[i] = f2bf(v);
}

// interleave Wg/Wu rows at 16-row granularity (8192 x 1024)
__global__ void k_build_wcat(const float* __restrict__ wgw, const float* __restrict__ wuw,
                             unsigned short* __restrict__ out) {
    int i = blockIdx.x * 256 + threadIdx.x;      // 8192*1024
    if (i >= 8192 * 1024) return;
    int j = i >> 10, k = i & 1023;
    int blk = j >> 5, r = j & 31;
    float v = (r < 16) ? wgw[(blk * 16 + r) * 1024 + k]
                       : wuw[(blk * 16 + (r - 16)) * 1024 + k];
    out[i] = f2bf(v);
}

// ---------------- rmsnorm (fp32 in -> bf16 out) ----------------------------
__global__ __launch_bounds__(256) void k_rmsnorm(const float* __restrict__ x,
                                                 const float* __restrict__ w,
                                                 unsigned short* __restrict__ out) {
    int row = blockIdx.x;
    const float4* xr = (const float4*)(x + (size_t)row * DIM);
    float4 v = xr[threadIdx.x];
    float ss = v.x * v.x + v.y * v.y + v.z * v.z + v.w * v.w;
    #pragma unroll
    for (int off = 32; off > 0; off >>= 1) ss += __shfl_down(ss, off, 64);
    __shared__ float p[4];
    if ((threadIdx.x & 63) == 0) p[threadIdx.x >> 6] = ss;
    __syncthreads();
    float tot = p[0] + p[1] + p[2] + p[3];
    float rms = rsqrtf(tot * (1.0f / DIM) + 1e-6f);
    float4 wv = ((const float4*)w)[threadIdx.x];
    ushort4 o;
    o.x = f2bf(v.x * rms * wv.x);
    o.y = f2bf(v.y * rms * wv.y);
    o.z = f2bf(v.z * rms * wv.z);
    o.w = f2bf(v.w * rms * wv.w);
    ((ushort4*)(out + (size_t)row * DIM))[threadIdx.x] = o;
}

// ---------------- 128x128 GEMM (kept for small/odd shapes) -----------------
// MODE 0: outF = C ; MODE 1: outF = resid + C ; MODE 3: SwiGLU -> bf16 N/2
template <int MODE>
__global__ __launch_bounds__(256) void k_gemm(const unsigned short* __restrict__ A,
                                              const unsigned short* __restrict__ Bw,
                                              int M, int N, int K,
                                              const float* resid,
                                              float* outF,
                                              unsigned short* outB) {
    __shared__ unsigned short As[128 * 32];
    __shared__ unsigned short Bs[128 * 32];
    const int tid = threadIdx.x;
    const int l   = tid & 63;
    const int wid = tid >> 6;
    const int wr  = wid >> 1, wc = wid & 1;
    const int m0  = blockIdx.x * 128, n0 = blockIdx.y * 128;

    f32x4 acc[4][4];
    #pragma unroll
    for (int i = 0; i < 4; ++i)
        #pragma unroll
        for (int j = 0; j < 4; ++j) acc[i][j] = f32x4{0.f, 0.f, 0.f, 0.f};

    const int c0 = tid, c1 = tid + 256;
    const unsigned short* a0 = A + (size_t)(m0 + (c0 >> 2)) * K + (c0 & 3) * 8;
    const unsigned short* a1 = A + (size_t)(m0 + (c1 >> 2)) * K + (c1 & 3) * 8;
    const unsigned short* b0 = Bw + (size_t)(n0 + (c0 >> 2)) * K + (c0 & 3) * 8;
    const unsigned short* b1 = Bw + (size_t)(n0 + (c1 >> 2)) * K + (c1 & 3) * 8;
    unsigned short* lA0 = &As[c0 * 8];
    unsigned short* lA1 = &As[c1 * 8];
    unsigned short* lB0 = &Bs[c0 * 8];
    unsigned short* lB1 = &Bs[c1 * 8];

    for (int kt = 0; kt < K; kt += 32) {
        gload_lds16(a0 + kt, lA0);
        gload_lds16(a1 + kt, lA1);
        gload_lds16(b0 + kt, lB0);
        gload_lds16(b1 + kt, lB1);
        __syncthreads();

        bf16x8 af[4], bfr[4];
        #pragma unroll
        for (int mf = 0; mf < 4; ++mf)
            af[mf] = *(const bf16x8*)&As[(wr * 64 + mf * 16 + (l & 15)) * 32 + (l >> 4) * 8];
        #pragma unroll
        for (int nf = 0; nf < 4; ++nf)
            bfr[nf] = *(const bf16x8*)&Bs[(wc * 64 + nf * 16 + (l & 15)) * 32 + (l >> 4) * 8];
        #pragma unroll
        for (int mf = 0; mf < 4; ++mf)
            #pragma unroll
            for (int nf = 0; nf < 4; ++nf)
                acc[mf][nf] = __builtin_amdgcn_mfma_f32_16x16x32_bf16(af[mf], bfr[nf], acc[mf][nf], 0, 0, 0);
        __syncthreads();
    }

    const int rbase = m0 + wr * 64 + (l >> 4) * 4;
    const int cbase = n0 + wc * 64 + (l & 15);
    if constexpr (MODE == 3) {
        const int halfN = N >> 1;
        const int cb = (n0 >> 1) + wc * 32 + (l & 15);
        #pragma unroll
        for (int mf = 0; mf < 4; ++mf)
            #pragma unroll
            for (int p = 0; p < 2; ++p)
                #pragma unroll
                for (int r = 0; r < 4; ++r) {
                    float g = acc[mf][2 * p][r];
                    float u = acc[mf][2 * p + 1][r];
                    float s = g / (1.f + expf(-g));
                    int row = rbase + mf * 16 + r;
                    outB[(size_t)row * halfN + cb + p * 16] = f2bf(s * u);
                }
    } else {
        #pragma unroll
        for (int mf = 0; mf < 4; ++mf)
            #pragma unroll
            for (int nf = 0; nf < 4; ++nf)
                #pragma unroll
                for (int r = 0; r < 4; ++r) {
                    int row = rbase + mf * 16 + r;
                    int col = cbase + nf * 16;
                    size_t idx = (size_t)row * N + col;
                    float v = acc[mf][nf][r];
                    if constexpr (MODE == 0) outF[idx] = v;
                    if constexpr (MODE == 1) outF[idx] = resid[idx] + v;
                }
    }
}

// ---------------- 256x256 8-wave GEMM, swizzled LDS + counted vmcnt --------
// C = A(MxK) * Bw(NxK)^T. M,N multiples of 256; K multiple of 64.
// LDS: 2 slots x {A[256][64], B[256][64]} bf16 = 128 KiB.
// Swizzle: 16B-chunk index ^= (row & 7); source pre-swizzled for
// global_load_lds (linear dest), ds_read applies the same XOR.
// Schedule: while computing tile t (4 quadrant phases), stage tile t+1
// one half-tile per phase; at each tile boundary s_waitcnt vmcnt(2)
// retires exactly the 8 loads of the tile about to be computed.
// MODE 1: outF = resid + C ; MODE 2: outB = bf16(C) ; MODE 3: SwiGLU N/2.
template <int MODE>
__global__ __launch_bounds__(512, 2) void k_gemm8(const unsigned short* __restrict__ A,
                                                  const unsigned short* __restrict__ Bw,
                                                  int M, int N, int K,
                                                  const float* resid,
                                                  float* outF,
                                                  unsigned short* outB) {
    __shared__ unsigned short lds[2][2][256 * 64];
    const int tid = threadIdx.x;          // 0..511
    const int l   = tid & 63;
    const int wid = tid >> 6;             // 0..7
    const int wm  = wid >> 2;             // 0..1  (M-half)
    const int wn  = wid & 3;              // 0..3  (N-quarter)
    const int m0  = blockIdx.x * 256, n0 = blockIdx.y * 256;
    const int sr  = tid >> 3;             // staging row within half (0..63)
    const int scc = (tid & 7) ^ (sr & 7); // pre-swizzled 16B source chunk

    f32x4 acc[8][4];
    #pragma unroll
    for (int i = 0; i < 8; ++i)
        #pragma unroll
        for (int j = 0; j < 4; ++j) acc[i][j] = f32x4{0.f, 0.f, 0.f, 0.f};

    const int NT = K >> 6;

    // stage half h (rows h*128..h*128+127) of matrix mat for K-tile t -> slot
    auto stage = [&](int slot, int mat, int h, int t) {
        const unsigned short* src = mat ? Bw : A;
        const int rb = (mat ? n0 : m0) + h * 128 + sr;
        const unsigned short* p = src + (size_t)rb * K + t * 64 + scc * 8;
        unsigned short* d = &lds[slot][mat][(h * 1024 + tid) * 8];
        gload_lds16(p, d);
        gload_lds16(p + (size_t)64 * K, d + 512 * 8);
    };

    // prologue: tile 0 fully staged into slot 0 (8 loads in flight)
    stage(0, 0, 0, 0); stage(0, 0, 1, 0); stage(0, 1, 0, 0); stage(0, 1, 1, 0);

    for (int t = 0; t < NT; ++t) {
        const int slot = t & 1;
        const int nslot = slot ^ 1;
        if (t + 1 < NT) {
            stage(nslot, 0, 0, t + 1);                 // next tile, half A0
            asm volatile("s_waitcnt vmcnt(2)" ::: "memory");  // tile t landed
        } else {
            asm volatile("s_waitcnt vmcnt(0)" ::: "memory");
        }
        SBAR();
        #pragma unroll
        for (int q = 0; q < 4; ++q) {
            if (t + 1 < NT) {
                if (q == 1) stage(nslot, 0, 1, t + 1);
                if (q == 2) stage(nslot, 1, 0, t + 1);
                if (q == 3) stage(nslot, 1, 1, t + 1);
            }
            const int mq = q >> 1, nq = q & 1;
            __builtin_amdgcn_s_setprio(1);
            #pragma unroll
            for (int ks = 0; ks < 2; ++ks) {
                const int kchunk = (ks * 4 + (l >> 4)) ^ (l & 7);
                bf16x8 af[4], bv[2];
                #pragma unroll
                for (int i = 0; i < 4; ++i)
                    af[i] = *(const bf16x8*)&lds[slot][0][((wm * 128 + (mq * 4 + i) * 16 + (l & 15)) * 8 + kchunk) * 8];
                #pragma unroll
                for (int j = 0; j < 2; ++j)
                    bv[j] = *(const bf16x8*)&lds[slot][1][((wn * 64 + (nq * 2 + j) * 16 + (l & 15)) * 8 + kchunk) * 8];
                #pragma unroll
                for (int i = 0; i < 4; ++i)
                    #pragma unroll
                    for (int j = 0; j < 2; ++j)
                        acc[mq * 4 + i][nq * 2 + j] =
                            __builtin_amdgcn_mfma_f32_16x16x32_bf16(af[i], bv[j], acc[mq * 4 + i][nq * 2 + j], 0, 0, 0);
            }
            __builtin_amdgcn_s_setprio(0);
            SBAR();
        }
    }

    const int rb = m0 + wm * 128 + (l >> 4) * 4;
    const int cb = n0 + wn * 64 + (l & 15);
    if constexpr (MODE == 3) {
        const int halfN = N >> 1;
        const int cc = (n0 >> 1) + wn * 32 + (l & 15);
        #pragma unroll
        for (int mf = 0; mf < 8; ++mf)
            #pragma unroll
            for (int p = 0; p < 2; ++p)
                #pragma unroll
                for (int r = 0; r < 4; ++r) {
                    float g = acc[mf][2 * p][r];
                    float u = acc[mf][2 * p + 1][r];
                    float s = g / (1.f + expf(-g));
                    int row = rb + mf * 16 + r;
                    outB[(size_t)row * halfN + cc + p * 16] = f2bf(s * u);
                }
    } else {
        #pragma unroll
        for (int mf = 0; mf < 8; ++mf)
            #pragma unroll
            for (int nf = 0; nf < 4; ++nf)
                #pragma unroll
                for (int r = 0; r < 4; ++r) {
                    int row = rb + mf * 16 + r;
                    int col = cb + nf * 16;
                    size_t idx = (size_t)row * N + col;
                    float v = acc[mf][nf][r];
                    if constexpr (MODE == 1) outF[idx] = resid[idx] + v;
                    if constexpr (MODE == 2) outB[idx] = f2bf(v);
                }
    }
}

// ---------------- gated causal depthwise conv ------------------------------
__global__ __launch_bounds__(256) void k_conv(const unsigned short* __restrict__ gv,
                                              const float* __restrict__ cw,
                                              unsigned short* __restrict__ cg) {
    __shared__ unsigned short vs[78 * 256];
    const int d  = blockIdx.x * 256 + threadIdx.x;
    const int t0 = blockIdx.y * 64;
    const int b  = blockIdx.z;
    const size_t base = (size_t)b * BN_T * 2048;
    for (int r = 0; r < 78; ++r) {
        int t = t0 - 14 + r;
        vs[r * 256 + threadIdx.x] = (t >= 0) ? gv[base + (size_t)t * 2048 + 1024 + d]
                                             : (unsigned short)0;
    }
    float wreg[NKER];
    #pragma unroll
    for (int k = 0; k < NKER; ++k) wreg[k] = cw[d * NKER + k];
    __syncthreads();
    for (int tl = 0; tl < 64; ++tl) {
        float acc = 0.f;
        #pragma unroll
        for (int k = 0; k < NKER; ++k)
            acc += wreg[k] * bf2f(vs[(tl + k) * 256 + threadIdx.x]);
        int t = t0 + tl;
        float gl = bf2f(gv[base + (size_t)t * 2048 + d]);
        float g  = 1.f / (1.f + expf(-gl));
        cg[((size_t)b * BN_T + t) * DIM + d] = f2bf(acc * g);
    }
}

// ---------------- small projections postprocess ----------------------------
__global__ void k_small(const float* __restrict__ logits, float* __restrict__ wg,
                        float* __restrict__ wv, float* __restrict__ rw) {
    int row = blockIdx.x * 256 + threadIdx.x;
    if (row >= BT_TOT) return;
    const float* lp = logits + (size_t)row * 128;
    #pragma unroll
    for (int s = 0; s < 8; ++s) wg[row * 8 + s] = 1.f / (1.f + expf(-lp[s]));
    #pragma unroll
    for (int e = 0; e < 32; ++e) wv[row * 32 + e] = lp[8 + e];
    float m = -1e30f;
    #pragma unroll
    for (int s = 0; s < 8; ++s) m = fmaxf(m, lp[40 + s]);
    float ex[8], sum = 0.f;
    #pragma unroll
    for (int s = 0; s < 8; ++s) { ex[s] = expf(lp[40 + s] - m); sum += ex[s]; }
    float inv = 1.f / sum;
    #pragma unroll
    for (int s = 0; s < 8; ++s) rw[row * 8 + s] = ex[s] * inv;
}

// ---------------- chunked affine scan (3 phases) ---------------------------
__global__ __launch_bounds__(256) void k_scan1(const float* __restrict__ wg,
                                               const float* __restrict__ wv,
                                               float* __restrict__ Ac,
                                               float* __restrict__ Bc) {
    const int c = blockIdx.x, b = blockIdx.y;
    const int s = threadIdx.x >> 5, sd = threadIdx.x & 31;
    const size_t tbase = (size_t)b * BN_T + (size_t)c * CHUNK;
    float A = 1.f, Bst = 0.f;
    #pragma unroll
    for (int i = 0; i < CHUNK; ++i) {
        float w = wg[(tbase + i) * 8 + s];
        float v = wv[(tbase + i) * 32 + sd];
        Bst = w * v + (1.f - w) * Bst;
        A *= (1.f - w);
    }
    const size_t idx = ((size_t)b * NCHUNK + c) * 256 + threadIdx.x;
    Ac[idx] = A;
    Bc[idx] = Bst;
}

__global__ __launch_bounds__(256) void k_scan2(const float* __restrict__ Ac,
                                               const float* __restrict__ Bc,
                                               const float* __restrict__ mem0,
                                               float* __restrict__ S0,
                                               float* __restrict__ curout) {
    const int b = blockIdx.x;
    const int tid = threadIdx.x;
    float st = mem0[b * 256 + tid];
    size_t idx = (size_t)b * NCHUNK * 256 + tid;
    float a0 = Ac[idx], b0 = Bc[idx];
    for (int c = 0; c < NCHUNK; ++c) {
        float a1 = 0.f, b1 = 0.f;
        if (c + 1 < NCHUNK) {
            a1 = Ac[idx + 256];
            b1 = Bc[idx + 256];
        }
        S0[idx] = st;
        st = a0 * st + b0;
        a0 = a1; b0 = b1;
        idx += 256;
    }
    curout[b * 256 + tid] = st;
}

__global__ __launch_bounds__(256) void k_scan3(const float* __restrict__ wg,
                                               const float* __restrict__ wv,
                                               const float* __restrict__ rw,
                                               const float* __restrict__ S0,
                                               unsigned short* __restrict__ stackw) {
    const int c = blockIdx.x, b = blockIdx.y;
    const int s = threadIdx.x >> 5, sd = threadIdx.x & 31;
    const size_t tbase = (size_t)b * BN_T + (size_t)c * CHUNK;
    float cur = S0[((size_t)b * NCHUNK + c) * 256 + threadIdx.x];
    #pragma unroll
    for (int i = 0; i < CHUNK; ++i) {
        float w = wg[(tbase + i) * 8 + s];
        float v = wv[(tbase + i) * 32 + sd];
        cur = w * v + (1.f - w) * cur;
        stackw[(tbase + i) * 256 + threadIdx.x] = f2bf(rw[(tbase + i) * 8 + s] * cur);
    }
}

// ---------------------------------------------------------------------------
extern "C" void kernel_launch(void* const* d_in, const int* in_sizes, int n_in,
                              void* d_out, int out_size, void* d_ws, size_t ws_size,
                              hipStream_t stream) {
    const float* x      = (const float*)d_in[0];
    const float* mem0   = (const float*)d_in[1];
    const float* ln1    = (const float*)d_in[2];
    const float* muw    = (const float*)d_in[3];
    const float* cw     = (const float*)d_in[4];
    const float* mdw    = (const float*)d_in[5];
    const float* lnm    = (const float*)d_in[6];
    const float* wgate  = (const float*)d_in[7];
    const float* wval   = (const float*)d_in[8];
    const float* rquery = (const float*)d_in[9];
    const float* rout   = (const float*)d_in[10];
    const float* ln2    = (const float*)d_in[11];
    const float* wgw    = (const float*)d_in[12];
    const float* wuw    = (const float*)d_in[13];
    const float* wow    = (const float*)d_in[14];
    float* out = (float*)d_out;
    char* ws = (char*)d_ws;

    // big layout (248 MiB): R 128MiB | h_buf 32 | x2 64 | w_cat 16 | w_wo 8
    // fallback (216 MiB):   R  96MiB | h_buf 32 | x2 64 | w_cat 16 | w_wo 8
    const bool big = ws_size >= (size_t)260046848;   // 248 MiB
    const size_t R_SZ = big ? 134217728 : 100663296;
    char* R = ws;
    unsigned short* gv     = (unsigned short*)(R + 0);
    unsigned short* cg     = (unsigned short*)(R + 67108864);
    float*          logits = (float*)(R + 0);
    unsigned short* stackw = (unsigned short*)(R + 8388608);
    float*          wgf    = (float*)(R + 16777216);
    float*          wvf    = (float*)(R + 17301504);
    float*          rwf    = (float*)(R + 19398656);
    float*          scanA  = (float*)(R + 20971520);
    float*          scanB  = (float*)(R + 22020096);
    float*          scanS0 = (float*)(R + 23068672);
    unsigned short* ff     = (unsigned short*)(R + 0);          // FFN intermediate
    unsigned short* h_buf  = (unsigned short*)(ws + R_SZ);              // 32 MiB
    float*          x2     = (float*)(ws + R_SZ + 33554432);            // 64 MiB
    unsigned short* w_cat  = (unsigned short*)(ws + R_SZ + 100663296);  // 16 MiB
    unsigned short* w_any  = w_cat;
    unsigned short* w_wo   = (unsigned short*)(ws + R_SZ + 117440512);  // 8 MiB

    // ---- mixer ----
    k_cvt<<<dim3(2048), 256, 0, stream>>>(muw, w_any, 524288);            // 2048x1024
    k_rmsnorm<<<dim3(BT_TOT), 256, 0, stream>>>(x, ln1, h_buf);
    k_gemm8<2><<<dim3(64, 8), 512, 0, stream>>>(h_buf, w_any, BT_TOT, 2048, 1024,
                                                nullptr, nullptr, gv);
    k_conv<<<dim3(4, 64, 4), 256, 0, stream>>>(gv, cw, cg);
    k_cvt<<<dim3(1024), 256, 0, stream>>>(mdw, w_any, 262144);            // 1024x1024
    k_gemm8<1><<<dim3(64, 4), 512, 0, stream>>>(cg, w_any, BT_TOT, 1024, 1024,
                                                x, x2, nullptr);

    // ---- story memory ----
    k_rmsnorm<<<dim3(BT_TOT), 256, 0, stream>>>(x2, lnm, h_buf);
    k_build_small<<<dim3(512), 256, 0, stream>>>(wgate, wval, rquery, w_any);
    k_gemm<0><<<dim3(128, 1), 256, 0, stream>>>(h_buf, w_any, BT_TOT, 128, 1024,
                                                nullptr, logits, nullptr);
    k_small<<<dim3(64), 256, 0, stream>>>(logits, wgf, wvf, rwf);
    k_scan1<<<dim3(NCHUNK, 4), 256, 0, stream>>>(wgf, wvf, scanA, scanB);
    k_scan2<<<dim3(4), 256, 0, stream>>>(scanA, scanB, mem0, scanS0, out + 16777216);
    k_scan3<<<dim3(NCHUNK, 4), 256, 0, stream>>>(wgf, wvf, rwf, scanS0, stackw);
    k_cvt<<<dim3(256), 256, 0, stream>>>(rout, w_any, 65536);             // 1024x256
    k_gemm8<1><<<dim3(64, 4), 512, 0, stream>>>(stackw, w_any, BT_TOT, 1024, 256,
                                                x2, x2, nullptr);          // in-place resid

    // ---- SwiGLU FFN ----
    k_rmsnorm<<<dim3(BT_TOT), 256, 0, stream>>>(x2, ln2, h_buf);
    k_build_wcat<<<dim3(32768), 256, 0, stream>>>(wgw, wuw, w_cat);
    k_cvt<<<dim3(4096), 256, 0, stream>>>(wow, w_wo, 1048576);            // 1024x4096
    if (big) {
        k_gemm8<3><<<dim3(64, 32), 512, 0, stream>>>(h_buf, w_cat, BT_TOT, 8192, 1024,
                                                     nullptr, nullptr, ff);
        k_gemm8<1><<<dim3(64, 4), 512, 0, stream>>>(ff, w_wo, BT_TOT, 1024, 4096,
                                                    x2, out, nullptr);
    } else {
        for (int c = 0; c < 2; ++c) {
            const size_t ro = (size_t)c * 8192;
            k_gemm8<3><<<dim3(32, 32), 512, 0, stream>>>(h_buf + ro * 1024, w_cat,
                                                         8192, 8192, 1024,
                                                         nullptr, nullptr, ff);
            k_gemm<1><<<dim3(64, 8), 256, 0, stream>>>(ff, w_wo, 8192, 1024, 4096,
                                                       x2 + ro * 1024, out + ro * 1024, nullptr);
        }
    }
}

// Round 6
// 965.115 us; speedup vs baseline: 1.6599x; 1.0116x over previous
//
#include <hip/hip_runtime.h>

// ---------------------------------------------------------------------------
// StoryMemoryBlock  (B=4, T=4096, D=1024, DF=4096, K=15, S=8, SD=32)
// R6: k_gemm8 inner loop rebuilt — fragment hoisting (24 ds_read_b128/tile
// instead of 48; LDS pipe was the binding resource at 4608 vs 2483 MFMA
// cycles), two ks-phases per K-tile following the m201 template
// {ds_read || stage -> barrier -> lgkmcnt(0) -> setprio MFMA -> barrier},
// counted vmcnt(4), plus bijective XCD-aware block swizzle (T1).
// ---------------------------------------------------------------------------

#define BN_T 4096
#define DIM 1024
#define BT_TOT (4 * 4096)          // 16384 rows
#define NKER 15
#define CHUNK 16
#define NCHUNK 256                 // 4096 / 16

typedef __bf16 bf16x8 __attribute__((ext_vector_type(8)));
typedef float  f32x4  __attribute__((ext_vector_type(4)));

__device__ __forceinline__ unsigned short f2bf(float f) {
    unsigned int u = __float_as_uint(f);
    u = u + 0x7FFFu + ((u >> 16) & 1u);           // RNE
    return (unsigned short)(u >> 16);
}
__device__ __forceinline__ float bf2f(unsigned short s) {
    return __uint_as_float(((unsigned int)s) << 16);
}

__device__ __forceinline__ void gload_lds16(const unsigned short* g, unsigned short* l) {
    __builtin_amdgcn_global_load_lds((const __attribute__((address_space(1))) void*)g,
                                     (__attribute__((address_space(3))) void*)l, 16, 0, 0);
}

#define SBAR() asm volatile("s_barrier" ::: "memory")

// ---------------- weight conversion helpers --------------------------------
__global__ void k_cvt(const float* __restrict__ in, unsigned short* __restrict__ out, int n4) {
    int i = blockIdx.x * 256 + threadIdx.x;
    if (i < n4) {
        float4 v = ((const float4*)in)[i];
        ushort4 o;
        o.x = f2bf(v.x); o.y = f2bf(v.y); o.z = f2bf(v.z); o.w = f2bf(v.w);
        ((ushort4*)out)[i] = o;
    }
}

__global__ void k_build_small(const float* __restrict__ wg, const float* __restrict__ wv,
                              const float* __restrict__ rq, unsigned short* __restrict__ out) {
    int i = blockIdx.x * 256 + threadIdx.x;      // 128*1024
    if (i >= 128 * 1024) return;
    int r = i >> 10, k = i & 1023;
    float v = 0.f;
    if (r < 8)       v = wg[r * 1024 + k];
    else if (r < 40) v = wv[(r - 8) * 1024 + k];
    else if (r < 48) v = rq[(r - 40) * 1024 + k];
    out[i] = f2bf(v);
}

// interleave Wg/Wu rows at 16-row granularity (8192 x 1024)
__global__ void k_build_wcat(const float* __restrict__ wgw, const float* __restrict__ wuw,
                             unsigned short* __restrict__ out) {
    int i = blockIdx.x * 256 + threadIdx.x;      // 8192*1024
    if (i >= 8192 * 1024) return;
    int j = i >> 10, k = i & 1023;
    int blk = j >> 5, r = j & 31;
    float v = (r < 16) ? wgw[(blk * 16 + r) * 1024 + k]
                       : wuw[(blk * 16 + (r - 16)) * 1024 + k];
    out[i] = f2bf(v);
}

// ---------------- rmsnorm (fp32 in -> bf16 out) ----------------------------
__global__ __launch_bounds__(256) void k_rmsnorm(const float* __restrict__ x,
                                                 const float* __restrict__ w,
                                                 unsigned short* __restrict__ out) {
    int row = blockIdx.x;
    const float4* xr = (const float4*)(x + (size_t)row * DIM);
    float4 v = xr[threadIdx.x];
    float ss = v.x * v.x + v.y * v.y + v.z * v.z + v.w * v.w;
    #pragma unroll
    for (int off = 32; off > 0; off >>= 1) ss += __shfl_down(ss, off, 64);
    __shared__ float p[4];
    if ((threadIdx.x & 63) == 0) p[threadIdx.x >> 6] = ss;
    __syncthreads();
    float tot = p[0] + p[1] + p[2] + p[3];
    float rms = rsqrtf(tot * (1.0f / DIM) + 1e-6f);
    float4 wv = ((const float4*)w)[threadIdx.x];
    ushort4 o;
    o.x = f2bf(v.x * rms * wv.x);
    o.y = f2bf(v.y * rms * wv.y);
    o.z = f2bf(v.z * rms * wv.z);
    o.w = f2bf(v.w * rms * wv.w);
    ((ushort4*)(out + (size_t)row * DIM))[threadIdx.x] = o;
}

// ---------------- 128x128 GEMM (kept for small/odd shapes) -----------------
template <int MODE>
__global__ __launch_bounds__(256) void k_gemm(const unsigned short* __restrict__ A,
                                              const unsigned short* __restrict__ Bw,
                                              int M, int N, int K,
                                              const float* resid,
                                              float* outF,
                                              unsigned short* outB) {
    __shared__ unsigned short As[128 * 32];
    __shared__ unsigned short Bs[128 * 32];
    const int tid = threadIdx.x;
    const int l   = tid & 63;
    const int wid = tid >> 6;
    const int wr  = wid >> 1, wc = wid & 1;
    const int m0  = blockIdx.x * 128, n0 = blockIdx.y * 128;

    f32x4 acc[4][4];
    #pragma unroll
    for (int i = 0; i < 4; ++i)
        #pragma unroll
        for (int j = 0; j < 4; ++j) acc[i][j] = f32x4{0.f, 0.f, 0.f, 0.f};

    const int c0 = tid, c1 = tid + 256;
    const unsigned short* a0 = A + (size_t)(m0 + (c0 >> 2)) * K + (c0 & 3) * 8;
    const unsigned short* a1 = A + (size_t)(m0 + (c1 >> 2)) * K + (c1 & 3) * 8;
    const unsigned short* b0 = Bw + (size_t)(n0 + (c0 >> 2)) * K + (c0 & 3) * 8;
    const unsigned short* b1 = Bw + (size_t)(n0 + (c1 >> 2)) * K + (c1 & 3) * 8;
    unsigned short* lA0 = &As[c0 * 8];
    unsigned short* lA1 = &As[c1 * 8];
    unsigned short* lB0 = &Bs[c0 * 8];
    unsigned short* lB1 = &Bs[c1 * 8];

    for (int kt = 0; kt < K; kt += 32) {
        gload_lds16(a0 + kt, lA0);
        gload_lds16(a1 + kt, lA1);
        gload_lds16(b0 + kt, lB0);
        gload_lds16(b1 + kt, lB1);
        __syncthreads();

        bf16x8 af[4], bfr[4];
        #pragma unroll
        for (int mf = 0; mf < 4; ++mf)
            af[mf] = *(const bf16x8*)&As[(wr * 64 + mf * 16 + (l & 15)) * 32 + (l >> 4) * 8];
        #pragma unroll
        for (int nf = 0; nf < 4; ++nf)
            bfr[nf] = *(const bf16x8*)&Bs[(wc * 64 + nf * 16 + (l & 15)) * 32 + (l >> 4) * 8];
        #pragma unroll
        for (int mf = 0; mf < 4; ++mf)
            #pragma unroll
            for (int nf = 0; nf < 4; ++nf)
                acc[mf][nf] = __builtin_amdgcn_mfma_f32_16x16x32_bf16(af[mf], bfr[nf], acc[mf][nf], 0, 0, 0);
        __syncthreads();
    }

    const int rbase = m0 + wr * 64 + (l >> 4) * 4;
    const int cbase = n0 + wc * 64 + (l & 15);
    if constexpr (MODE == 3) {
        const int halfN = N >> 1;
        const int cb = (n0 >> 1) + wc * 32 + (l & 15);
        #pragma unroll
        for (int mf = 0; mf < 4; ++mf)
            #pragma unroll
            for (int p = 0; p < 2; ++p)
                #pragma unroll
                for (int r = 0; r < 4; ++r) {
                    float g = acc[mf][2 * p][r];
                    float u = acc[mf][2 * p + 1][r];
                    float s = g / (1.f + expf(-g));
                    int row = rbase + mf * 16 + r;
                    outB[(size_t)row * halfN + cb + p * 16] = f2bf(s * u);
                }
    } else {
        #pragma unroll
        for (int mf = 0; mf < 4; ++mf)
            #pragma unroll
            for (int nf = 0; nf < 4; ++nf)
                #pragma unroll
                for (int r = 0; r < 4; ++r) {
                    int row = rbase + mf * 16 + r;
                    int col = cbase + nf * 16;
                    size_t idx = (size_t)row * N + col;
                    float v = acc[mf][nf][r];
                    if constexpr (MODE == 0) outF[idx] = v;
                    if constexpr (MODE == 1) outF[idx] = resid[idx] + v;
                }
    }
}

// ---------------- 256x256 8-wave GEMM, hoisted frags + 2-phase template ----
// C = A(MxK) * Bw(NxK)^T. M,N multiples of 256; K multiple of 64.
// LDS: 2 slots x {A[256][64], B[256][64]} bf16 = 128 KiB.
// Swizzle (T2): LDS[row][chunk j] = G[row][j ^ (row&7)] via pre-swizzled
// global source + linear global_load_lds dest; ds_read XORs the same.
// Per K-tile: 2 phases (ks=0,1). Each phase: 12 ds_read_b128 (8 A + 4 B,
// each frag read ONCE) || stage 2 half-tiles of t+1 -> s_barrier ->
// lgkmcnt(0) -> setprio(1) 32 MFMA setprio(0) -> s_barrier.
// vmcnt(4) at tile top: tile t's 8 loads retired, 4 of t+1 in flight.
// T1: bijective XCD swizzle on flattened wg id (all grids nwg%8==0).
template <int MODE>
__global__ __launch_bounds__(512, 2) void k_gemm8(const unsigned short* __restrict__ A,
                                                  const unsigned short* __restrict__ Bw,
                                                  int M, int N, int K,
                                                  const float* resid,
                                                  float* outF,
                                                  unsigned short* outB) {
    __shared__ unsigned short lds[2][2][256 * 64];
    const int tid = threadIdx.x;          // 0..511
    const int l   = tid & 63;
    const int wid = tid >> 6;             // 0..7
    const int wm  = wid >> 2;             // 0..1  (M-half)
    const int wn  = wid & 3;              // 0..3  (N-quarter)

    // T1 bijective XCD swizzle (requires nwg % 8 == 0, true for all call sites)
    const int nwg  = gridDim.x * gridDim.y;
    int bid = blockIdx.y * gridDim.x + blockIdx.x;
    if ((nwg & 7) == 0) bid = (bid & 7) * (nwg >> 3) + (bid >> 3);
    const int bx = bid % gridDim.x;       // M-tile
    const int by = bid / gridDim.x;       // N-tile
    const int m0 = bx * 256, n0 = by * 256;

    const int sr  = tid >> 3;             // staging row within 128-half
    const int scc = (tid & 7) ^ (sr & 7); // pre-swizzled 16B source chunk

    f32x4 acc[8][4];
    #pragma unroll
    for (int i = 0; i < 8; ++i)
        #pragma unroll
        for (int j = 0; j < 4; ++j) acc[i][j] = f32x4{0.f, 0.f, 0.f, 0.f};

    const int NT = K >> 6;

    // stage half h (128 rows) of matrix mat for K-tile t -> slot (2 loads)
    auto stage = [&](int slot, int mat, int h, int t) {
        const unsigned short* src = mat ? Bw : A;
        const int rb = (mat ? n0 : m0) + h * 128 + sr;
        const unsigned short* p = src + (size_t)rb * K + t * 64 + scc * 8;
        unsigned short* d = &lds[slot][mat][(h * 1024 + tid) * 8];
        gload_lds16(p, d);
        gload_lds16(p + (size_t)64 * K, d + 512 * 8);
    };

    // prologue: tile 0 fully staged into slot 0 (8 loads in flight)
    stage(0, 0, 0, 0); stage(0, 0, 1, 0); stage(0, 1, 0, 0); stage(0, 1, 1, 0);

    for (int t = 0; t < NT; ++t) {
        const int slot = t & 1;
        const int nslot = slot ^ 1;
        if (t + 1 < NT) {
            stage(nslot, 0, 0, t + 1);                        // A halves of t+1
            stage(nslot, 0, 1, t + 1);
            asm volatile("s_waitcnt vmcnt(4)" ::: "memory");  // tile t landed
        } else {
            asm volatile("s_waitcnt vmcnt(0)" ::: "memory");
        }
        SBAR();
        #pragma unroll
        for (int ks = 0; ks < 2; ++ks) {
            const int kchunk = (ks * 4 + (l >> 4)) ^ (l & 7);
            bf16x8 af[8], bv[4];
            #pragma unroll
            for (int i = 0; i < 8; ++i)
                af[i] = *(const bf16x8*)&lds[slot][0][((wm * 128 + i * 16 + (l & 15)) * 8 + kchunk) * 8];
            #pragma unroll
            for (int j = 0; j < 4; ++j)
                bv[j] = *(const bf16x8*)&lds[slot][1][((wn * 64 + j * 16 + (l & 15)) * 8 + kchunk) * 8];
            if (ks == 0 && t + 1 < NT) {
                stage(nslot, 1, 0, t + 1);                    // B halves of t+1
                stage(nslot, 1, 1, t + 1);
            }
            SBAR();
            asm volatile("s_waitcnt lgkmcnt(0)" ::: "memory");
            __builtin_amdgcn_sched_barrier(0);
            __builtin_amdgcn_s_setprio(1);
            #pragma unroll
            for (int i = 0; i < 8; ++i)
                #pragma unroll
                for (int j = 0; j < 4; ++j)
                    acc[i][j] = __builtin_amdgcn_mfma_f32_16x16x32_bf16(af[i], bv[j], acc[i][j], 0, 0, 0);
            __builtin_amdgcn_s_setprio(0);
            SBAR();
        }
    }

    const int rb = m0 + wm * 128 + (l >> 4) * 4;
    const int cb = n0 + wn * 64 + (l & 15);
    if constexpr (MODE == 3) {
        const int halfN = N >> 1;
        const int cc = (n0 >> 1) + wn * 32 + (l & 15);
        #pragma unroll
        for (int mf = 0; mf < 8; ++mf)
            #pragma unroll
            for (int p = 0; p < 2; ++p)
                #pragma unroll
                for (int r = 0; r < 4; ++r) {
                    float g = acc[mf][2 * p][r];
                    float u = acc[mf][2 * p + 1][r];
                    float s = g / (1.f + expf(-g));
                    int row = rb + mf * 16 + r;
                    outB[(size_t)row * halfN + cc + p * 16] = f2bf(s * u);
                }
    } else {
        #pragma unroll
        for (int mf = 0; mf < 8; ++mf)
            #pragma unroll
            for (int nf = 0; nf < 4; ++nf)
                #pragma unroll
                for (int r = 0; r < 4; ++r) {
                    int row = rb + mf * 16 + r;
                    int col = cb + nf * 16;
                    size_t idx = (size_t)row * N + col;
                    float v = acc[mf][nf][r];
                    if constexpr (MODE == 1) outF[idx] = resid[idx] + v;
                    if constexpr (MODE == 2) outB[idx] = f2bf(v);
                }
    }
}

// ---------------- gated causal depthwise conv ------------------------------
__global__ __launch_bounds__(256) void k_conv(const unsigned short* __restrict__ gv,
                                              const float* __restrict__ cw,
                                              unsigned short* __restrict__ cg) {
    __shared__ unsigned short vs[78 * 256];
    const int d  = blockIdx.x * 256 + threadIdx.x;
    const int t0 = blockIdx.y * 64;
    const int b  = blockIdx.z;
    const size_t base = (size_t)b * BN_T * 2048;
    for (int r = 0; r < 78; ++r) {
        int t = t0 - 14 + r;
        vs[r * 256 + threadIdx.x] = (t >= 0) ? gv[base + (size_t)t * 2048 + 1024 + d]
                                             : (unsigned short)0;
    }
    float wreg[NKER];
    #pragma unroll
    for (int k = 0; k < NKER; ++k) wreg[k] = cw[d * NKER + k];
    __syncthreads();
    for (int tl = 0; tl < 64; ++tl) {
        float acc = 0.f;
        #pragma unroll
        for (int k = 0; k < NKER; ++k)
            acc += wreg[k] * bf2f(vs[(tl + k) * 256 + threadIdx.x]);
        int t = t0 + tl;
        float gl = bf2f(gv[base + (size_t)t * 2048 + d]);
        float g  = 1.f / (1.f + expf(-gl));
        cg[((size_t)b * BN_T + t) * DIM + d] = f2bf(acc * g);
    }
}

// ---------------- small projections postprocess ----------------------------
__global__ void k_small(const float* __restrict__ logits, float* __restrict__ wg,
                        float* __restrict__ wv, float* __restrict__ rw) {
    int row = blockIdx.x * 256 + threadIdx.x;
    if (row >= BT_TOT) return;
    const float* lp = logits + (size_t)row * 128;
    #pragma unroll
    for (int s = 0; s < 8; ++s) wg[row * 8 + s] = 1.f / (1.f + expf(-lp[s]));
    #pragma unroll
    for (int e = 0; e < 32; ++e) wv[row * 32 + e] = lp[8 + e];
    float m = -1e30f;
    #pragma unroll
    for (int s = 0; s < 8; ++s) m = fmaxf(m, lp[40 + s]);
    float ex[8], sum = 0.f;
    #pragma unroll
    for (int s = 0; s < 8; ++s) { ex[s] = expf(lp[40 + s] - m); sum += ex[s]; }
    float inv = 1.f / sum;
    #pragma unroll
    for (int s = 0; s < 8; ++s) rw[row * 8 + s] = ex[s] * inv;
}

// ---------------- chunked affine scan (3 phases) ---------------------------
__global__ __launch_bounds__(256) void k_scan1(const float* __restrict__ wg,
                                               const float* __restrict__ wv,
                                               float* __restrict__ Ac,
                                               float* __restrict__ Bc) {
    const int c = blockIdx.x, b = blockIdx.y;
    const int s = threadIdx.x >> 5, sd = threadIdx.x & 31;
    const size_t tbase = (size_t)b * BN_T + (size_t)c * CHUNK;
    float A = 1.f, Bst = 0.f;
    #pragma unroll
    for (int i = 0; i < CHUNK; ++i) {
        float w = wg[(tbase + i) * 8 + s];
        float v = wv[(tbase + i) * 32 + sd];
        Bst = w * v + (1.f - w) * Bst;
        A *= (1.f - w);
    }
    const size_t idx = ((size_t)b * NCHUNK + c) * 256 + threadIdx.x;
    Ac[idx] = A;
    Bc[idx] = Bst;
}

__global__ __launch_bounds__(256) void k_scan2(const float* __restrict__ Ac,
                                               const float* __restrict__ Bc,
                                               const float* __restrict__ mem0,
                                               float* __restrict__ S0,
                                               float* __restrict__ curout) {
    const int b = blockIdx.x;
    const int tid = threadIdx.x;
    float st = mem0[b * 256 + tid];
    size_t idx = (size_t)b * NCHUNK * 256 + tid;
    float a0 = Ac[idx], b0 = Bc[idx];
    for (int c = 0; c < NCHUNK; ++c) {
        float a1 = 0.f, b1 = 0.f;
        if (c + 1 < NCHUNK) {
            a1 = Ac[idx + 256];
            b1 = Bc[idx + 256];
        }
        S0[idx] = st;
        st = a0 * st + b0;
        a0 = a1; b0 = b1;
        idx += 256;
    }
    curout[b * 256 + tid] = st;
}

__global__ __launch_bounds__(256) void k_scan3(const float* __restrict__ wg,
                                               const float* __restrict__ wv,
                                               const float* __restrict__ rw,
                                               const float* __restrict__ S0,
                                               unsigned short* __restrict__ stackw) {
    const int c = blockIdx.x, b = blockIdx.y;
    const int s = threadIdx.x >> 5, sd = threadIdx.x & 31;
    const size_t tbase = (size_t)b * BN_T + (size_t)c * CHUNK;
    float cur = S0[((size_t)b * NCHUNK + c) * 256 + threadIdx.x];
    #pragma unroll
    for (int i = 0; i < CHUNK; ++i) {
        float w = wg[(tbase + i) * 8 + s];
        float v = wv[(tbase + i) * 32 + sd];
        cur = w * v + (1.f - w) * cur;
        stackw[(tbase + i) * 256 + threadIdx.x] = f2bf(rw[(tbase + i) * 8 + s] * cur);
    }
}

// ---------------------------------------------------------------------------
extern "C" void kernel_launch(void* const* d_in, const int* in_sizes, int n_in,
                              void* d_out, int out_size, void* d_ws, size_t ws_size,
                              hipStream_t stream) {
    const float* x      = (const float*)d_in[0];
    const float* mem0   = (const float*)d_in[1];
    const float* ln1    = (const float*)d_in[2];
    const float* muw    = (const float*)d_in[3];
    const float* cw     = (const float*)d_in[4];
    const float* mdw    = (const float*)d_in[5];
    const float* lnm    = (const float*)d_in[6];
    const float* wgate  = (const float*)d_in[7];
    const float* wval   = (const float*)d_in[8];
    const float* rquery = (const float*)d_in[9];
    const float* rout   = (const float*)d_in[10];
    const float* ln2    = (const float*)d_in[11];
    const float* wgw    = (const float*)d_in[12];
    const float* wuw    = (const float*)d_in[13];
    const float* wow    = (const float*)d_in[14];
    float* out = (float*)d_out;
    char* ws = (char*)d_ws;

    // big layout (248 MiB): R 128MiB | h_buf 32 | x2 64 | w_cat 16 | w_wo 8
    // fallback (216 MiB):   R  96MiB | h_buf 32 | x2 64 | w_cat 16 | w_wo 8
    const bool big = ws_size >= (size_t)260046848;   // 248 MiB
    const size_t R_SZ = big ? 134217728 : 100663296;
    char* R = ws;
    unsigned short* gv     = (unsigned short*)(R + 0);
    unsigned short* cg     = (unsigned short*)(R + 67108864);
    float*          logits = (float*)(R + 0);
    unsigned short* stackw = (unsigned short*)(R + 8388608);
    float*          wgf    = (float*)(R + 16777216);
    float*          wvf    = (float*)(R + 17301504);
    float*          rwf    = (float*)(R + 19398656);
    float*          scanA  = (float*)(R + 20971520);
    float*          scanB  = (float*)(R + 22020096);
    float*          scanS0 = (float*)(R + 23068672);
    unsigned short* ff     = (unsigned short*)(R + 0);          // FFN intermediate
    unsigned short* h_buf  = (unsigned short*)(ws + R_SZ);              // 32 MiB
    float*          x2     = (float*)(ws + R_SZ + 33554432);            // 64 MiB
    unsigned short* w_cat  = (unsigned short*)(ws + R_SZ + 100663296);  // 16 MiB
    unsigned short* w_any  = w_cat;
    unsigned short* w_wo   = (unsigned short*)(ws + R_SZ + 117440512);  // 8 MiB

    // ---- mixer ----
    k_cvt<<<dim3(2048), 256, 0, stream>>>(muw, w_any, 524288);            // 2048x1024
    k_rmsnorm<<<dim3(BT_TOT), 256, 0, stream>>>(x, ln1, h_buf);
    k_gemm8<2><<<dim3(64, 8), 512, 0, stream>>>(h_buf, w_any, BT_TOT, 2048, 1024,
                                                nullptr, nullptr, gv);
    k_conv<<<dim3(4, 64, 4), 256, 0, stream>>>(gv, cw, cg);
    k_cvt<<<dim3(1024), 256, 0, stream>>>(mdw, w_any, 262144);            // 1024x1024
    k_gemm8<1><<<dim3(64, 4), 512, 0, stream>>>(cg, w_any, BT_TOT, 1024, 1024,
                                                x, x2, nullptr);

    // ---- story memory ----
    k_rmsnorm<<<dim3(BT_TOT), 256, 0, stream>>>(x2, lnm, h_buf);
    k_build_small<<<dim3(512), 256, 0, stream>>>(wgate, wval, rquery, w_any);
    k_gemm<0><<<dim3(128, 1), 256, 0, stream>>>(h_buf, w_any, BT_TOT, 128, 1024,
                                                nullptr, logits, nullptr);
    k_small<<<dim3(64), 256, 0, stream>>>(logits, wgf, wvf, rwf);
    k_scan1<<<dim3(NCHUNK, 4), 256, 0, stream>>>(wgf, wvf, scanA, scanB);
    k_scan2<<<dim3(4), 256, 0, stream>>>(scanA, scanB, mem0, scanS0, out + 16777216);
    k_scan3<<<dim3(NCHUNK, 4), 256, 0, stream>>>(wgf, wvf, rwf, scanS0, stackw);
    k_cvt<<<dim3(256), 256, 0, stream>>>(rout, w_any, 65536);             // 1024x256
    k_gemm8<1><<<dim3(64, 4), 512, 0, stream>>>(stackw, w_any, BT_TOT, 1024, 256,
                                                x2, x2, nullptr);          // in-place resid

    // ---- SwiGLU FFN ----
    k_rmsnorm<<<dim3(BT_TOT), 256, 0, stream>>>(x2, ln2, h_buf);
    k_build_wcat<<<dim3(32768), 256, 0, stream>>>(wgw, wuw, w_cat);
    k_cvt<<<dim3(4096), 256, 0, stream>>>(wow, w_wo, 1048576);            // 1024x4096
    if (big) {
        k_gemm8<3><<<dim3(64, 32), 512, 0, stream>>>(h_buf, w_cat, BT_TOT, 8192, 1024,
                                                     nullptr, nullptr, ff);
        k_gemm8<1><<<dim3(64, 4), 512, 0, stream>>>(ff, w_wo, BT_TOT, 1024, 4096,
                                                    x2, out, nullptr);
    } else {
        for (int c = 0; c < 2; ++c) {
            const size_t ro = (size_t)c * 8192;
            k_gemm8<3><<<dim3(32, 32), 512, 0, stream>>>(h_buf + ro * 1024, w_cat,
                                                         8192, 8192, 1024,
                                                         nullptr, nullptr, ff);
            k_gemm<1><<<dim3(64, 8), 256, 0, stream>>>(ff, w_wo, 8192, 1024, 4096,
                                                       x2 + ro * 1024, out + ro * 1024, nullptr);
        }
    }
}